// Round 8
// baseline (201.342 us; speedup 1.0000x reference)
//
#include <hip/hip_runtime.h>

// 8 x 512 x 512 f32 -> 17x17 windows @ stride 4 -> 124x124 windows/batch -> (8,68) means.
// R21 = R20 (verified best: 105.8us total, feat 54.3us @ 77% VALUBusy) + fused reduce via
// per-channel float atomics (single-variable change):
//  - emit paths atomicAdd directly into out[b*68+ch] instead of storing per-tile partials;
//    out zeroed by a 2176B hipMemsetAsync (stream-ordered, capture-legal, R19-proven).
//  - NOT R19's ticket scheme: no tail __syncthreads (that pinned 12 waves, -18% VALUBusy),
//    no ACQ_REL RMW chain. Contention trivial: 128 adds per (b,ch) over ~54us.
//  - Removes reduce kernel (~3us) + dispatch gap (~4us) + 278KB part round-trip.
//  - Also a tolerance probe: atomic order != tree-reduce order, so absmax should go small-
//    nonzero. Session-long absmax 0.0 alongside __log2f (can't be bitwise vs JAX) implies
//    tolerance-based comparison; confirming unlocks float-regrouping restructures later.
// Feature kernel (unchanged from R20): one 768-thr (12-wave) block per 16x8-window tile;
// fused ballot phase A with batched loads; lane = 2 vertically-adjacent windows via phase
// counters A/S/B (w1=A+S, w2=S+B); LDS pre-sliced per-(row,ly) 17-bit level masks as uint4;
// SEGRUN unroll-1 with row prefetch; off-diag bins via disjoint-union popc.
// Wave roles (wid): 0 stats ch0-3 | 1 hist ch4-7 | 2:(0,1)k0 3:(1,0)k2 4:(0,2)k4
//   5:(1,1)k1,k5 6:(0,4)k8 7:(1,-1)k3,k7 8:(2,0)k6 9:(3,3)k9 10:(4,0)k10 11:(3,-3)k11
// ws: unused.

#define G_MEAN_F 85.384f
#define G_STD_F  53.798f

__device__ constexpr int LO15[15] = {0,0,0,0,0,1,1,1,1,2,2,2,3,3,4};
__device__ constexpr int HI15[15] = {0,1,2,3,4,1,2,3,4,2,3,4,3,4,4};

__device__ __forceinline__ float wred(float v) {
#pragma unroll
  for (int m = 32; m; m >>= 1) v += __shfl_xor(v, m, 64);
  return v;
}

// Load pre-sliced levels 1-4 for slice index (row*8+ly); level 0 by complement.
__device__ __forceinline__ void load_sl(const unsigned* sl, int idx, unsigned m[5]) {
  const uint4 q = *(const uint4*)(sl + idx * 4);
  m[1] = q.x; m[2] = q.y; m[3] = q.z; m[4] = q.w;
  m[0] = 0x1FFFFu & ~(m[1] | m[2] | m[3] | m[4]);
}

// cnt[u] += popc over 15 unordered bins; off-diag sets disjoint -> popc of the union.
template<int DC>
__device__ __forceinline__ void updoff(unsigned* cnt, const unsigned a[5], const unsigned b[5]) {
  unsigned as[5], bs[5];
#pragma unroll
  for (int v = 0; v < 5; ++v) {
    as[v] = (DC < 0) ? (a[v] >> (-DC)) : a[v];
    bs[v] = (DC > 0) ? (b[v] >> DC) : b[v];
  }
#pragma unroll
  for (int u = 0; u < 15; ++u) {
    const int i = LO15[u], j = HI15[u];
    unsigned t = as[i] & bs[j];
    if (i != j) t |= as[j] & bs[i];
    cnt[u] += __popc(t);
  }
}

// GLCM features from symmetric-unordered pair counts (math verified R1-R12).
__device__ __forceinline__ void feat5(const unsigned* cnt, float Np,
                                      float& con, float& hom, float& ene,
                                      float& corr, float& ent) {
  const float invN = 1.0f / Np;
  const float inv2N = 0.5f / Np;
  con = 0.0f; hom = 0.0f; ent = 0.0f;
  float eac = 0.0f;
  float P[5] = {0, 0, 0, 0, 0};
#pragma unroll
  for (int u = 0; u < 15; ++u) {
    const int lo = LO15[u], hi = HI15[u];
    const float m = (float)cnt[u];
    const float d2 = (float)((hi - lo) * (hi - lo));
    con += m * d2;
    hom += m * (1.0f / (1.0f + d2));
    if (lo == hi) {
      eac += m * m;
      P[lo] += 2.0f * m;
      float g = m * invN;
      ent -= g * __log2f(g + 1e-8f);
    } else {
      eac += 0.5f * m * m;
      P[lo] += m; P[hi] += m;
      float g = m * inv2N;
      ent -= 2.0f * g * __log2f(g + 1e-8f);
    }
  }
  con *= invN;
  hom *= invN;
  ene = sqrtf(eac) * invN;
  float mu = 0.0f;
#pragma unroll
  for (int i = 0; i < 5; ++i) { P[i] *= inv2N; mu += (float)i * P[i]; }
  float s2 = 0.0f;
#pragma unroll
  for (int i = 0; i < 5; ++i) { float d = (float)i - mu; s2 = fmaf(P[i] * d, d, s2); }
  float denom = s2;
  float cov = 0.0f;
#pragma unroll
  for (int u = 0; u < 15; ++u)
    cov += ((float)cnt[u] * invN) * ((float)LO15[u] - mu) * ((float)HI15[u] - mu);
  corr = (denom < 1e-15f) ? 1.0f : cov / fmaxf(denom, 1e-30f);
}

// Emit both packed windows' features (summed, validity-masked) via atomics to out.
__device__ __forceinline__ void emit2(const unsigned c1[15], const unsigned c2[15], float Np,
                                      bool v1, bool v2, float* outb, int k0, int k1) {
  float con1, hom1, ene1, cor1, ent1, con2, hom2, ene2, cor2, ent2;
  feat5(c1, Np, con1, hom1, ene1, cor1, ent1);
  feat5(c2, Np, con2, hom2, ene2, cor2, ent2);
  if (!v1) { con1 = 0; hom1 = 0; ene1 = 0; cor1 = 0; ent1 = 0; }
  if (!v2) { con2 = 0; hom2 = 0; ene2 = 0; cor2 = 0; ent2 = 0; }
  float con = wred(con1 + con2), hom = wred(hom1 + hom2), ene = wred(ene1 + ene2);
  float cor = wred(cor1 + cor2), ent = wred(ent1 + ent2);
  if ((threadIdx.x & 63) == 0) {
    const float s = 1.0f / 15376.0f;
    atomicAdd(outb + (8 + k0), con * s);
    atomicAdd(outb + (20 + k0), hom * s);
    atomicAdd(outb + (32 + k0), ene * s);
    atomicAdd(outb + (44 + k0), cor * s);
    atomicAdd(outb + (56 + k0), ent * s);
    if (k1 >= 0) {
      atomicAdd(outb + (8 + k1), con * s);
      atomicAdd(outb + (20 + k1), hom * s);
      atomicAdd(outb + (32 + k1), ene * s);
      atomicAdd(outb + (44 + k1), cor * s);
      atomicAdd(outb + (56 + k1), ent * s);
    }
  }
}

// One offset over 2 vertically-adjacent windows. Phases: A rows R<4 (w1 only),
// S rows [4,17-DR) (shared), B rows [17-DR,21-DR) (w2 only). Each LDS row loaded ONCE;
// next row prefetched before the current row's AND/POPC body (covers ds_read latency).
// (Exact R13/R10 rolling-buffer scheme — verified.)
template<int DR, int DC>
__device__ void glcm2(const unsigned* sl, int s, int ly, bool v1, bool v2,
                      float Np, float* outb, int k0, int k1) {
  unsigned A[15], S[15], B[15];
#pragma unroll
  for (int u = 0; u < 15; ++u) { A[u] = 0; S[u] = 0; B[u] = 0; }
  unsigned buf[DR > 0 ? DR : 1][5];
  if constexpr (DR > 0) {
#pragma unroll
    for (int i = 0; i < DR; ++i) load_sl(sl, (s + i) * 8 + ly, buf[i]);
  }
  unsigned nxt[5];
  load_sl(sl, (s + DR) * 8 + ly, nxt);

#define SEGRUN(CNT, RB, RE)                                              \
  _Pragma("unroll 1")                                                    \
  for (int R = (RB); R < (RE); ++R) {                                    \
    unsigned cur[5];                                                     \
    _Pragma("unroll")                                                    \
    for (int v = 0; v < 5; ++v) cur[v] = nxt[v];                         \
    load_sl(sl, (s + DR + R + 1) * 8 + ly, nxt); /* prefetch (padded) */ \
    if constexpr (DR > 0) {                                              \
      updoff<DC>(CNT, buf[0], cur);                                      \
      _Pragma("unroll")                                                  \
      for (int i = 0; i < DR - 1; ++i)                                   \
        _Pragma("unroll")                                                \
        for (int v = 0; v < 5; ++v) buf[i][v] = buf[i + 1][v];           \
      _Pragma("unroll")                                                  \
      for (int v = 0; v < 5; ++v) buf[DR > 0 ? DR - 1 : 0][v] = cur[v];  \
    } else {                                                             \
      updoff<DC>(CNT, cur, cur);                                         \
    }                                                                    \
  }

  SEGRUN(A, 0, 4)
  SEGRUN(S, 4, 17 - DR)
  SEGRUN(B, 17 - DR, 21 - DR)
#undef SEGRUN

#pragma unroll
  for (int u = 0; u < 15; ++u) { A[u] += S[u]; B[u] += S[u]; }
  emit2(A, B, Np, v1, v2, outb, k0, k1);
}

// ---------- Kernel: features accumulated straight into out via atomics ----------
// Phase A builds the slice table from x via per-row wave ballots; all loads issued first.
__global__ __launch_bounds__(768)
void glcm_feat_kernel(const float* __restrict__ x,
                      float* __restrict__ out) {
  __shared__ __align__(16) unsigned sl[79 * 8 * 4];  // pre-sliced masks + 2 pad rows, 10112 B

  const int tid = threadIdx.x;
  const int lane = tid & 63;
  const int wid = tid >> 6;
  const int ty = blockIdx.x;     // 0..15
  const int tx = blockIdx.y;     // 0..7
  const int b = blockIdx.z;
  const int px0 = tx * 64;
  const int py0 = ty * 32;
  const float* xb = x + (size_t)b * 512 * 512;

  const float T1 = 0.5f;
  const float T2 = (float)(85.384 - 53.798);
  const float T3 = 85.384f;
  const float T4 = (float)(85.384 + 53.798);

  // Phase A (fused mask build), latency-hidden: issue all row loads first, then ballots.
  // Wave w covers rows {w, w+12, ...} < 77 (waves 0-4: 7 rows; 5-11: 6). Extra slots
  // load a clamped in-bounds address and are discarded. Slice math identical to R18/R20
  // (bit-identical sl: cols>=512 inactive == old zero pad; rows>511 clamped).
  {
    const int col = py0 + lane;
    const int colc = col > 511 ? 511 : col;
    const bool act = (lane < 45) && (col < 512);
    float xv[7];
#pragma unroll
    for (int i = 0; i < 7; ++i) {
      int row = wid + 12 * i; if (row > 76) row = 76;       // clamp: dummy in-bounds load
      int gr = px0 + row; if (gr > 511) gr = 511;
      xv[i] = xb[(size_t)gr * 512 + colc];
    }
#pragma unroll
    for (int i = 0; i < 7; ++i) {
      const int row = wid + 12 * i;
      if (row < 77) {                                        // wave-uniform guard
        const float v = xv[i];
        const int q = (int)(v >= T1) + (int)(v >= T2) + (int)(v >= T3) + (int)(v >= T4);
        const unsigned long long b1 = __ballot(act && q == 1);
        const unsigned long long b2 = __ballot(act && q == 2);
        const unsigned long long b3 = __ballot(act && q == 3);
        const unsigned long long b4 = __ballot(act && q == 4);
        if (lane < 8) {
          const int sh4 = 4 * lane;
          const unsigned s0 = (unsigned)(b1 >> sh4) & 0x1FFFFu;
          const unsigned s1 = (unsigned)(b2 >> sh4) & 0x1FFFFu;
          const unsigned s2 = (unsigned)(b3 >> sh4) & 0x1FFFFu;
          const unsigned s3 = (unsigned)(b4 >> sh4) & 0x1FFFFu;
          *(uint4*)(sl + (row * 8 + lane) * 4) = make_uint4(s0, s1, s2, s3);
        }
      }
    }
  }
  if (tid < 16) {  // zero pad rows 77,78 (prefetch overrun region, never consumed)
    *(uint4*)(sl + (77 * 8 + tid) * 4) = make_uint4(0u, 0u, 0u, 0u);
  }
  __syncthreads();

  // Lane = (lxp, ly): window pair wx1 = tx*16 + 2*lxp (+1); wy = ty*8 + ly.
  const int lxp = lane >> 3, ly = lane & 7;
  const int wx1 = tx * 16 + 2 * lxp;
  const int wy = ty * 8 + ly;
  const bool vy = (wy < 124);
  const bool v1 = (wx1 < 124) && vy;
  const bool v2 = (wx1 + 1 < 124) && vy;
  const int s = 8 * lxp;            // tile-local pixel row of w1
  float* outb = out + b * 68;       // per-batch output row (atomic accumulation)

  if (wid == 0) {
    // ---- float stats (ch 0-3), phases A/S/B over 21 rows (verified R8) ----
    int sp = px0 + s; if (sp > 488) sp = 488;
    int c0 = py0 + 4 * ly; if (c0 > 492) c0 = 492;
    const float* fw = xb + (size_t)sp * 512 + c0;
    float sA = 0, qA = 0, sS = 0, qS = 0, sB = 0, qB = 0;
    float mxA = -1e30f, mnA = 1e30f, mxS = -1e30f, mnS = 1e30f, mxB = -1e30f, mnB = 1e30f;
#pragma unroll 1
    for (int r = 0; r < 21; ++r) {
      const float* p = fw + r * 512;
      const float4* p4 = (const float4*)p;
      float rs = 0, rq = 0, rmx = -1e30f, rmn = 1e30f;
#pragma unroll
      for (int w = 0; w < 4; ++w) {
        float4 f = p4[w];
        rs += f.x; rq = fmaf(f.x, f.x, rq); rmx = fmaxf(rmx, f.x); rmn = fminf(rmn, f.x);
        rs += f.y; rq = fmaf(f.y, f.y, rq); rmx = fmaxf(rmx, f.y); rmn = fminf(rmn, f.y);
        rs += f.z; rq = fmaf(f.z, f.z, rq); rmx = fmaxf(rmx, f.z); rmn = fminf(rmn, f.z);
        rs += f.w; rq = fmaf(f.w, f.w, rq); rmx = fmaxf(rmx, f.w); rmn = fminf(rmn, f.w);
      }
      float t = p[16];
      rs += t; rq = fmaf(t, t, rq); rmx = fmaxf(rmx, t); rmn = fminf(rmn, t);
      if (r < 4)       { sA += rs; qA += rq; mxA = fmaxf(mxA, rmx); mnA = fminf(mnA, rmn); }
      else if (r < 17) { sS += rs; qS += rq; mxS = fmaxf(mxS, rmx); mnS = fminf(mnS, rmn); }
      else             { sB += rs; qB += rq; mxB = fmaxf(mxB, rmx); mnB = fminf(mnB, rmn); }
    }
    float ch[4][2];
#pragma unroll
    for (int w = 0; w < 2; ++w) {
      float sum = w ? (sS + sB) : (sA + sS);
      float ssq = w ? (qS + qB) : (qA + qS);
      float mx = w ? fmaxf(mxS, mxB) : fmaxf(mxA, mxS);
      float mn = w ? fminf(mnS, mnB) : fminf(mnA, mnS);
      float mean = sum * (1.0f / 289.0f);
      float var = fmaxf(ssq * (1.0f / 289.0f) - mean * mean, 0.0f);
      float fm = mean / G_MEAN_F;
      ch[0][w] = fm;
      ch[1][w] = sqrtf(var) / G_STD_F;
      ch[2][w] = (mx - fm) / G_STD_F;
      ch[3][w] = (fm - mn) / G_STD_F;
    }
#pragma unroll
    for (int c = 0; c < 4; ++c) {
      float f = (v1 ? ch[c][0] : 0.0f) + (v2 ? ch[c][1] : 0.0f);
      f = wred(f);
      if (lane == 0) atomicAdd(outb + c, f * (1.0f / 15376.0f));
    }
  } else if (wid == 1) {
    // ---- value histogram (ch 4-7) from slice popcounts, phases A/S/B (verified R8) ----
    unsigned hA[4] = {0,0,0,0}, hS[4] = {0,0,0,0}, hB[4] = {0,0,0,0};
#pragma unroll 1
    for (int R = 0; R < 21; ++R) {
      const uint4 q = *(const uint4*)(sl + ((s + R) * 8 + ly) * 4);
      unsigned* h = (R < 4) ? hA : (R < 17) ? hS : hB;
      h[0] += __popc(q.x); h[1] += __popc(q.y); h[2] += __popc(q.z); h[3] += __popc(q.w);
    }
    float ch[4][2];
#pragma unroll
    for (int w = 0; w < 2; ++w) {
      unsigned t1 = w ? (hS[0] + hB[0]) : (hA[0] + hS[0]);
      unsigned t2 = w ? (hS[1] + hB[1]) : (hA[1] + hS[1]);
      unsigned t3 = w ? (hS[2] + hB[2]) : (hA[2] + hS[2]);
      unsigned t4 = w ? (hS[3] + hB[3]) : (hA[3] + hS[3]);
      unsigned tot = t1 + t2 + t3 + t4;
      float ti = (tot > 0) ? 1.0f / (float)tot : 0.0f;
      ch[0][w] = (float)t1 * ti;
      ch[1][w] = (float)t2 * ti;
      ch[2][w] = (float)t3 * ti;
      ch[3][w] = (float)t4 * ti;
    }
#pragma unroll
    for (int c = 0; c < 4; ++c) {
      float f = (v1 ? ch[c][0] : 0.0f) + (v2 ? ch[c][1] : 0.0f);
      f = wred(f);
      if (lane == 0) atomicAdd(outb + (4 + c), f * (1.0f / 15376.0f));
    }
  } else if (wid == 2) {
    glcm2<0, 1>(sl, s, ly, v1, v2, 272.0f, outb, 0, -1);
  } else if (wid == 3) {
    glcm2<1, 0>(sl, s, ly, v1, v2, 272.0f, outb, 2, -1);
  } else if (wid == 4) {
    glcm2<0, 2>(sl, s, ly, v1, v2, 255.0f, outb, 4, -1);
  } else if (wid == 5) {
    glcm2<1, 1>(sl, s, ly, v1, v2, 256.0f, outb, 1, 5);
  } else if (wid == 6) {
    glcm2<0, 4>(sl, s, ly, v1, v2, 221.0f, outb, 8, -1);
  } else if (wid == 7) {
    glcm2<1, -1>(sl, s, ly, v1, v2, 256.0f, outb, 3, 7);
  } else if (wid == 8) {
    glcm2<2, 0>(sl, s, ly, v1, v2, 255.0f, outb, 6, -1);
  } else if (wid == 9) {
    glcm2<3, 3>(sl, s, ly, v1, v2, 196.0f, outb, 9, -1);
  } else if (wid == 10) {
    glcm2<4, 0>(sl, s, ly, v1, v2, 221.0f, outb, 10, -1);
  } else {
    glcm2<3, -3>(sl, s, ly, v1, v2, 196.0f, outb, 11, -1);
  }
}

extern "C" void kernel_launch(void* const* d_in, const int* in_sizes, int n_in,
                              void* d_out, int out_size, void* d_ws, size_t ws_size,
                              hipStream_t stream)
{
  const float* x = (const float*)d_in[0];
  float* out = (float*)d_out;

  hipMemsetAsync(out, 0, 8 * 68 * sizeof(float), stream);
  glcm_feat_kernel<<<dim3(16, 8, 8), dim3(768), 0, stream>>>(x, out);
}

// Round 9
// 100.710 us; speedup vs baseline: 1.9992x; 1.9992x over previous
//
#include <hip/hip_runtime.h>

// 8 x 512 x 512 f32 -> 17x17 windows @ stride 4 -> 124x124 windows/batch -> (8,68) means.
// R22 = R20 (verified best: 105.8us, feat 54.3us @ 77% VALUBusy) + GLCM marginal
// derivation (single-variable change, integer-exact):
//  - levels 0-4 partition every position, so the 5 level-0 bins are linear in the 10
//    bins among levels 1-4, the per-level marginals popc(a_j&W)/popc(b_j&W), and the
//    constant Np=(17-DR)(17-|DC|):
//      M[0,j] = marg_a[j]+marg_b[j] - 2 M[j,j] - sum_{k!=j,k>=1} M[j,k]
//      M[0,0] = Np - sum(other 14)
//    Derivation is exact integer math -> cnt[15] bit-identical -> absmax 0.
//  - per-row GLCM cost: 59 -> 44-48 VALU ops (-19% DC!=0, -27% DC=0); level-0
//    complement dropped from load_sl; epilogue derivation ~86 ops/wave (amortized ~8%).
//  - accumulators 45 -> 54/lane (10 bins + 8 marginals x 3 phases); VGPR ~88-96, same
//    occupancy bucket (proven insensitive R14-R16).
// R21 post-mortem: fused atomic reduce catastrophically serialized (feat 54->135us,
// VALUBusy 77->32%); ALL cross-block combining stays in the separate ~3us reduce kernel.
// Feature kernel: one 768-thr (12-wave) block per 16x8-window tile; fused ballot phase A
// with batched loads (R20-verified); lane = 2 vertically-adjacent windows via phase
// counters A/S/B (w1=A+S, w2=S+B); LDS pre-sliced per-(row,ly) 17-bit level masks as
// uint4; SEGRUN unroll-1 with row prefetch.
// Wave roles (wid): 0 stats ch0-3 | 1 hist ch4-7 | 2:(0,1)k0 3:(1,0)k2 4:(0,2)k4
//   5:(1,1)k1,k5 6:(0,4)k8 7:(1,-1)k3,k7 8:(2,0)k6 9:(3,3)k9 10:(4,0)k10 11:(3,-3)k11
// ws: float part[8][68][128] (278528 B).

#define G_MEAN_F 85.384f
#define G_STD_F  53.798f

__device__ constexpr int LO15[15] = {0,0,0,0,0,1,1,1,1,2,2,2,3,3,4};
__device__ constexpr int HI15[15] = {0,1,2,3,4,1,2,3,4,2,3,4,3,4,4};

__device__ __forceinline__ float wred(float v) {
#pragma unroll
  for (int m = 32; m; m >>= 1) v += __shfl_xor(v, m, 64);
  return v;
}

// Load pre-sliced levels 1-4 for slice index (row*8+ly). No level-0 complement needed.
__device__ __forceinline__ void load_sl4(const unsigned* sl, int idx, unsigned m[4]) {
  const uint4 q = *(const uint4*)(sl + idx * 4);
  m[0] = q.x; m[1] = q.y; m[2] = q.z; m[3] = q.w;
}

// Accumulate 10 unordered bins among levels 1-4 plus 8 per-level marginals.
// c[0..9]: (1,1)(1,2)(1,3)(1,4)(2,2)(2,3)(2,4)(3,3)(3,4)(4,4)  [= LO15/HI15 order 5..14]
// c[10..13]: marg_a[1..4]  (pairs where a-side level = j)
// c[14..17]: marg_b[1..4]  (pairs where b-side level = j)
// Shifted side is confined by the shift; unshifted side is masked by WM.
template<int DC>
__device__ __forceinline__ void upd10(unsigned* c, const unsigned a[4], const unsigned b[4]) {
  constexpr int AD = DC < 0 ? -DC : 0;
  constexpr int BD = DC > 0 ? DC : 0;
  constexpr unsigned WM = 0x1FFFFu >> (DC < 0 ? -DC : DC);
  unsigned as[4], bs[4];
#pragma unroll
  for (int v = 0; v < 4; ++v) {
    as[v] = a[v] >> AD;
    bs[v] = b[v] >> BD;
  }
  int u = 0;
#pragma unroll
  for (int i = 0; i < 4; ++i) {
    c[u] += __popc(as[i] & bs[i]); ++u;
#pragma unroll
    for (int j = i + 1; j < 4; ++j) {
      c[u] += __popc((as[i] & bs[j]) | (as[j] & bs[i])); ++u;
    }
  }
#pragma unroll
  for (int v = 0; v < 4; ++v) {
    const unsigned ma = (DC > 0) ? (as[v] & WM) : as[v];
    const unsigned mb = (DC < 0) ? (bs[v] & WM) : bs[v];
    c[10 + v] += __popc(ma);
    c[14 + v] += __popc(mb);
  }
}

// Derive the full 15-bin vector (LO15/HI15 order) from 10 bins + 8 marginals + Np.
// Exact integer identities (levels partition positions), valid for any mask data.
__device__ __forceinline__ void derive15(const unsigned t[18], unsigned NpI, unsigned cnt[15]) {
  // bins among 1..4 land at cnt[5..14] in matching order
#pragma unroll
  for (int u = 0; u < 10; ++u) cnt[5 + u] = t[u];
  // t bin index map: (1,1)=0 (1,2)=1 (1,3)=2 (1,4)=3 (2,2)=4 (2,3)=5 (2,4)=6 (3,3)=7 (3,4)=8 (4,4)=9
  cnt[1] = t[10] + t[14] - 2u * t[0] - (t[1] + t[2] + t[3]);   // M[0,1]
  cnt[2] = t[11] + t[15] - 2u * t[4] - (t[1] + t[5] + t[6]);   // M[0,2]
  cnt[3] = t[12] + t[16] - 2u * t[7] - (t[2] + t[5] + t[8]);   // M[0,3]
  cnt[4] = t[13] + t[17] - 2u * t[9] - (t[3] + t[6] + t[8]);   // M[0,4]
  unsigned sum = cnt[1] + cnt[2] + cnt[3] + cnt[4];
#pragma unroll
  for (int u = 0; u < 10; ++u) sum += t[u];
  cnt[0] = NpI - sum;                                          // M[0,0]
}

// GLCM features from symmetric-unordered pair counts (math verified R1-R12).
__device__ __forceinline__ void feat5(const unsigned* cnt, float Np,
                                      float& con, float& hom, float& ene,
                                      float& corr, float& ent) {
  const float invN = 1.0f / Np;
  const float inv2N = 0.5f / Np;
  con = 0.0f; hom = 0.0f; ent = 0.0f;
  float eac = 0.0f;
  float P[5] = {0, 0, 0, 0, 0};
#pragma unroll
  for (int u = 0; u < 15; ++u) {
    const int lo = LO15[u], hi = HI15[u];
    const float m = (float)cnt[u];
    const float d2 = (float)((hi - lo) * (hi - lo));
    con += m * d2;
    hom += m * (1.0f / (1.0f + d2));
    if (lo == hi) {
      eac += m * m;
      P[lo] += 2.0f * m;
      float g = m * invN;
      ent -= g * __log2f(g + 1e-8f);
    } else {
      eac += 0.5f * m * m;
      P[lo] += m; P[hi] += m;
      float g = m * inv2N;
      ent -= 2.0f * g * __log2f(g + 1e-8f);
    }
  }
  con *= invN;
  hom *= invN;
  ene = sqrtf(eac) * invN;
  float mu = 0.0f;
#pragma unroll
  for (int i = 0; i < 5; ++i) { P[i] *= inv2N; mu += (float)i * P[i]; }
  float s2 = 0.0f;
#pragma unroll
  for (int i = 0; i < 5; ++i) { float d = (float)i - mu; s2 = fmaf(P[i] * d, d, s2); }
  float denom = s2;
  float cov = 0.0f;
#pragma unroll
  for (int u = 0; u < 15; ++u)
    cov += ((float)cnt[u] * invN) * ((float)LO15[u] - mu) * ((float)HI15[u] - mu);
  corr = (denom < 1e-15f) ? 1.0f : cov / fmaxf(denom, 1e-30f);
}

// Emit both packed windows' features (summed, validity-masked) to unique partial slots.
__device__ __forceinline__ void emit2(const unsigned c1[15], const unsigned c2[15], float Np,
                                      bool v1, bool v2, float* pt0, int k0, int k1) {
  float con1, hom1, ene1, cor1, ent1, con2, hom2, ene2, cor2, ent2;
  feat5(c1, Np, con1, hom1, ene1, cor1, ent1);
  feat5(c2, Np, con2, hom2, ene2, cor2, ent2);
  if (!v1) { con1 = 0; hom1 = 0; ene1 = 0; cor1 = 0; ent1 = 0; }
  if (!v2) { con2 = 0; hom2 = 0; ene2 = 0; cor2 = 0; ent2 = 0; }
  float con = wred(con1 + con2), hom = wred(hom1 + hom2), ene = wred(ene1 + ene2);
  float cor = wred(cor1 + cor2), ent = wred(ent1 + ent2);
  if ((threadIdx.x & 63) == 0) {
    const float s = 1.0f / 15376.0f;
    pt0[(8 + k0) * 128] = con * s;
    pt0[(20 + k0) * 128] = hom * s;
    pt0[(32 + k0) * 128] = ene * s;
    pt0[(44 + k0) * 128] = cor * s;
    pt0[(56 + k0) * 128] = ent * s;
    if (k1 >= 0) {
      pt0[(8 + k1) * 128] = con * s;
      pt0[(20 + k1) * 128] = hom * s;
      pt0[(32 + k1) * 128] = ene * s;
      pt0[(44 + k1) * 128] = cor * s;
      pt0[(56 + k1) * 128] = ent * s;
    }
  }
}

// One offset over 2 vertically-adjacent windows. Phases: A rows R<4 (w1 only),
// S rows [4,17-DR) (shared), B rows [17-DR,21-DR) (w2 only). Each LDS row loaded ONCE;
// next row prefetched before the current row's AND/POPC body. 18 accumulators/phase
// (10 bins + 8 marginals); full 15-bin vectors derived once at the end (integer-exact).
template<int DR, int DC>
__device__ void glcm2(const unsigned* sl, int s, int ly, bool v1, bool v2,
                      float Np, float* pt0, int k0, int k1) {
  constexpr int ADC = DC < 0 ? -DC : DC;
  const unsigned NpI = (unsigned)((17 - DR) * (17 - ADC));
  unsigned A[18], S[18], B[18];
#pragma unroll
  for (int u = 0; u < 18; ++u) { A[u] = 0; S[u] = 0; B[u] = 0; }
  unsigned buf[DR > 0 ? DR : 1][4];
  if constexpr (DR > 0) {
#pragma unroll
    for (int i = 0; i < DR; ++i) load_sl4(sl, (s + i) * 8 + ly, buf[i]);
  }
  unsigned nxt[4];
  load_sl4(sl, (s + DR) * 8 + ly, nxt);

#define SEGRUN(CNT, RB, RE)                                              \
  _Pragma("unroll 1")                                                    \
  for (int R = (RB); R < (RE); ++R) {                                    \
    unsigned cur[4];                                                     \
    _Pragma("unroll")                                                    \
    for (int v = 0; v < 4; ++v) cur[v] = nxt[v];                         \
    load_sl4(sl, (s + DR + R + 1) * 8 + ly, nxt); /* prefetch (padded) */\
    if constexpr (DR > 0) {                                              \
      upd10<DC>(CNT, buf[0], cur);                                       \
      _Pragma("unroll")                                                  \
      for (int i = 0; i < DR - 1; ++i)                                   \
        _Pragma("unroll")                                                \
        for (int v = 0; v < 4; ++v) buf[i][v] = buf[i + 1][v];           \
      _Pragma("unroll")                                                  \
      for (int v = 0; v < 4; ++v) buf[DR > 0 ? DR - 1 : 0][v] = cur[v];  \
    } else {                                                             \
      upd10<DC>(CNT, cur, cur);                                          \
    }                                                                    \
  }

  SEGRUN(A, 0, 4)
  SEGRUN(S, 4, 17 - DR)
  SEGRUN(B, 17 - DR, 21 - DR)
#undef SEGRUN

  unsigned w1[18], w2[18];
#pragma unroll
  for (int u = 0; u < 18; ++u) { w1[u] = A[u] + S[u]; w2[u] = S[u] + B[u]; }
  unsigned cnt1[15], cnt2[15];
  derive15(w1, NpI, cnt1);
  derive15(w2, NpI, cnt2);
  emit2(cnt1, cnt2, Np, v1, v2, pt0, k0, k1);
}

// ---------- Kernel 1: features -> per-tile partials (one 12-wave block per tile) ----------
// Phase A builds the slice table from x via per-row wave ballots; all loads issued first.
__global__ __launch_bounds__(768)
void glcm_feat_kernel(const float* __restrict__ x,
                      float* __restrict__ part) {
  __shared__ __align__(16) unsigned sl[79 * 8 * 4];  // pre-sliced masks + 2 pad rows, 10112 B

  const int tid = threadIdx.x;
  const int lane = tid & 63;
  const int wid = tid >> 6;
  const int ty = blockIdx.x;     // 0..15
  const int tx = blockIdx.y;     // 0..7
  const int b = blockIdx.z;
  const int px0 = tx * 64;
  const int py0 = ty * 32;
  const float* xb = x + (size_t)b * 512 * 512;

  const float T1 = 0.5f;
  const float T2 = (float)(85.384 - 53.798);
  const float T3 = 85.384f;
  const float T4 = (float)(85.384 + 53.798);

  // Phase A (fused mask build), latency-hidden: issue all row loads first, then ballots.
  // Wave w covers rows {w, w+12, ...} < 77 (waves 0-4: 7 rows; 5-11: 6). Extra slots
  // load a clamped in-bounds address and are discarded. Slice math identical to R20
  // (bit-identical sl: cols>=512 inactive == old zero pad; rows>511 clamped).
  {
    const int col = py0 + lane;
    const int colc = col > 511 ? 511 : col;
    const bool act = (lane < 45) && (col < 512);
    float xv[7];
#pragma unroll
    for (int i = 0; i < 7; ++i) {
      int row = wid + 12 * i; if (row > 76) row = 76;       // clamp: dummy in-bounds load
      int gr = px0 + row; if (gr > 511) gr = 511;
      xv[i] = xb[(size_t)gr * 512 + colc];
    }
#pragma unroll
    for (int i = 0; i < 7; ++i) {
      const int row = wid + 12 * i;
      if (row < 77) {                                        // wave-uniform guard
        const float v = xv[i];
        const int q = (int)(v >= T1) + (int)(v >= T2) + (int)(v >= T3) + (int)(v >= T4);
        const unsigned long long b1 = __ballot(act && q == 1);
        const unsigned long long b2 = __ballot(act && q == 2);
        const unsigned long long b3 = __ballot(act && q == 3);
        const unsigned long long b4 = __ballot(act && q == 4);
        if (lane < 8) {
          const int sh4 = 4 * lane;
          const unsigned s0 = (unsigned)(b1 >> sh4) & 0x1FFFFu;
          const unsigned s1 = (unsigned)(b2 >> sh4) & 0x1FFFFu;
          const unsigned s2 = (unsigned)(b3 >> sh4) & 0x1FFFFu;
          const unsigned s3 = (unsigned)(b4 >> sh4) & 0x1FFFFu;
          *(uint4*)(sl + (row * 8 + lane) * 4) = make_uint4(s0, s1, s2, s3);
        }
      }
    }
  }
  if (tid < 16) {  // zero pad rows 77,78 (prefetch overrun region, never consumed)
    *(uint4*)(sl + (77 * 8 + tid) * 4) = make_uint4(0u, 0u, 0u, 0u);
  }
  __syncthreads();

  // Lane = (lxp, ly): window pair wx1 = tx*16 + 2*lxp (+1); wy = ty*8 + ly.
  const int lxp = lane >> 3, ly = lane & 7;
  const int wx1 = tx * 16 + 2 * lxp;
  const int wy = ty * 8 + ly;
  const bool vy = (wy < 124);
  const bool v1 = (wx1 < 124) && vy;
  const bool v2 = (wx1 + 1 < 124) && vy;
  const int s = 8 * lxp;            // tile-local pixel row of w1
  const int tile = tx * 16 + ty;    // 0..127
  float* pt0 = part + (size_t)b * 68 * 128 + tile;  // channel ch at pt0[ch*128]

  if (wid == 0) {
    // ---- float stats (ch 0-3), phases A/S/B over 21 rows (verified R8) ----
    int sp = px0 + s; if (sp > 488) sp = 488;
    int c0 = py0 + 4 * ly; if (c0 > 492) c0 = 492;
    const float* fw = xb + (size_t)sp * 512 + c0;
    float sA = 0, qA = 0, sS = 0, qS = 0, sB = 0, qB = 0;
    float mxA = -1e30f, mnA = 1e30f, mxS = -1e30f, mnS = 1e30f, mxB = -1e30f, mnB = 1e30f;
#pragma unroll 1
    for (int r = 0; r < 21; ++r) {
      const float* p = fw + r * 512;
      const float4* p4 = (const float4*)p;
      float rs = 0, rq = 0, rmx = -1e30f, rmn = 1e30f;
#pragma unroll
      for (int w = 0; w < 4; ++w) {
        float4 f = p4[w];
        rs += f.x; rq = fmaf(f.x, f.x, rq); rmx = fmaxf(rmx, f.x); rmn = fminf(rmn, f.x);
        rs += f.y; rq = fmaf(f.y, f.y, rq); rmx = fmaxf(rmx, f.y); rmn = fminf(rmn, f.y);
        rs += f.z; rq = fmaf(f.z, f.z, rq); rmx = fmaxf(rmx, f.z); rmn = fminf(rmn, f.z);
        rs += f.w; rq = fmaf(f.w, f.w, rq); rmx = fmaxf(rmx, f.w); rmn = fminf(rmn, f.w);
      }
      float t = p[16];
      rs += t; rq = fmaf(t, t, rq); rmx = fmaxf(rmx, t); rmn = fminf(rmn, t);
      if (r < 4)       { sA += rs; qA += rq; mxA = fmaxf(mxA, rmx); mnA = fminf(mnA, rmn); }
      else if (r < 17) { sS += rs; qS += rq; mxS = fmaxf(mxS, rmx); mnS = fminf(mnS, rmn); }
      else             { sB += rs; qB += rq; mxB = fmaxf(mxB, rmx); mnB = fminf(mnB, rmn); }
    }
    float ch[4][2];
#pragma unroll
    for (int w = 0; w < 2; ++w) {
      float sum = w ? (sS + sB) : (sA + sS);
      float ssq = w ? (qS + qB) : (qA + qS);
      float mx = w ? fmaxf(mxS, mxB) : fmaxf(mxA, mxS);
      float mn = w ? fminf(mnS, mnB) : fminf(mnA, mnS);
      float mean = sum * (1.0f / 289.0f);
      float var = fmaxf(ssq * (1.0f / 289.0f) - mean * mean, 0.0f);
      float fm = mean / G_MEAN_F;
      ch[0][w] = fm;
      ch[1][w] = sqrtf(var) / G_STD_F;
      ch[2][w] = (mx - fm) / G_STD_F;
      ch[3][w] = (fm - mn) / G_STD_F;
    }
#pragma unroll
    for (int c = 0; c < 4; ++c) {
      float f = (v1 ? ch[c][0] : 0.0f) + (v2 ? ch[c][1] : 0.0f);
      f = wred(f);
      if (lane == 0) pt0[c * 128] = f * (1.0f / 15376.0f);
    }
  } else if (wid == 1) {
    // ---- value histogram (ch 4-7) from slice popcounts, phases A/S/B (verified R8) ----
    unsigned hA[4] = {0,0,0,0}, hS[4] = {0,0,0,0}, hB[4] = {0,0,0,0};
#pragma unroll 1
    for (int R = 0; R < 21; ++R) {
      const uint4 q = *(const uint4*)(sl + ((s + R) * 8 + ly) * 4);
      unsigned* h = (R < 4) ? hA : (R < 17) ? hS : hB;
      h[0] += __popc(q.x); h[1] += __popc(q.y); h[2] += __popc(q.z); h[3] += __popc(q.w);
    }
    float ch[4][2];
#pragma unroll
    for (int w = 0; w < 2; ++w) {
      unsigned t1 = w ? (hS[0] + hB[0]) : (hA[0] + hS[0]);
      unsigned t2 = w ? (hS[1] + hB[1]) : (hA[1] + hS[1]);
      unsigned t3 = w ? (hS[2] + hB[2]) : (hA[2] + hS[2]);
      unsigned t4 = w ? (hS[3] + hB[3]) : (hA[3] + hS[3]);
      unsigned tot = t1 + t2 + t3 + t4;
      float ti = (tot > 0) ? 1.0f / (float)tot : 0.0f;
      ch[0][w] = (float)t1 * ti;
      ch[1][w] = (float)t2 * ti;
      ch[2][w] = (float)t3 * ti;
      ch[3][w] = (float)t4 * ti;
    }
#pragma unroll
    for (int c = 0; c < 4; ++c) {
      float f = (v1 ? ch[c][0] : 0.0f) + (v2 ? ch[c][1] : 0.0f);
      f = wred(f);
      if (lane == 0) pt0[(4 + c) * 128] = f * (1.0f / 15376.0f);
    }
  } else if (wid == 2) {
    glcm2<0, 1>(sl, s, ly, v1, v2, 272.0f, pt0, 0, -1);
  } else if (wid == 3) {
    glcm2<1, 0>(sl, s, ly, v1, v2, 272.0f, pt0, 2, -1);
  } else if (wid == 4) {
    glcm2<0, 2>(sl, s, ly, v1, v2, 255.0f, pt0, 4, -1);
  } else if (wid == 5) {
    glcm2<1, 1>(sl, s, ly, v1, v2, 256.0f, pt0, 1, 5);
  } else if (wid == 6) {
    glcm2<0, 4>(sl, s, ly, v1, v2, 221.0f, pt0, 8, -1);
  } else if (wid == 7) {
    glcm2<1, -1>(sl, s, ly, v1, v2, 256.0f, pt0, 3, 7);
  } else if (wid == 8) {
    glcm2<2, 0>(sl, s, ly, v1, v2, 255.0f, pt0, 6, -1);
  } else if (wid == 9) {
    glcm2<3, 3>(sl, s, ly, v1, v2, 196.0f, pt0, 9, -1);
  } else if (wid == 10) {
    glcm2<4, 0>(sl, s, ly, v1, v2, 221.0f, pt0, 10, -1);
  } else {
    glcm2<3, -3>(sl, s, ly, v1, v2, 196.0f, pt0, 11, -1);
  }
}

// ---------- Kernel 2: reduce 128 tile-partials per (batch,channel) ----------
__global__ __launch_bounds__(64)
void reduce_kernel(const float* __restrict__ part, float* __restrict__ out) {
  const int ch = blockIdx.x;
  const int b = blockIdx.y;
  const int lane = threadIdx.x;
  const float2* p = (const float2*)(part + ((size_t)b * 68 + ch) * 128);
  float2 f = p[lane];
  float v = f.x + f.y;
  v = wred(v);
  if (lane == 0) out[b * 68 + ch] = v;
}

extern "C" void kernel_launch(void* const* d_in, const int* in_sizes, int n_in,
                              void* d_out, int out_size, void* d_ws, size_t ws_size,
                              hipStream_t stream)
{
  const float* x = (const float*)d_in[0];
  float* out = (float*)d_out;
  float* part = (float*)d_ws;   // 278528 B

  glcm_feat_kernel<<<dim3(16, 8, 8), dim3(768), 0, stream>>>(x, part);
  reduce_kernel<<<dim3(68, 8), dim3(64), 0, stream>>>(part, out);
}